// Round 1
// baseline (6867.323 us; speedup 1.0000x reference)
//
#include <hip/hip_runtime.h>

#define N_NODES 50000
#define C_CH 64
#define N_SUB 4
#define M_TERMS 20

// ---------------- CSR build ----------------

__global__ void hist_kernel(const int* __restrict__ src, int* __restrict__ cnt, int E) {
    int e = blockIdx.x * blockDim.x + threadIdx.x;
    if (e < E) atomicAdd(&cnt[src[e]], 1);
}

// single-block exclusive scan over n counts -> row_ptr[0..n]
__global__ void scan_kernel(const int* __restrict__ cnt, int* __restrict__ row_ptr, int n) {
    __shared__ int wsum[16];
    __shared__ int carry;
    const int tid = threadIdx.x;
    const int lane = tid & 63;
    const int wv = tid >> 6;
    if (tid == 0) carry = 0;
    __syncthreads();
    for (int base = 0; base < n; base += 1024) {
        int i = base + tid;
        int v = (i < n) ? cnt[i] : 0;
        int s = v;
        #pragma unroll
        for (int off = 1; off < 64; off <<= 1) {
            int u = __shfl_up(s, off, 64);
            if (lane >= off) s += u;
        }
        if (lane == 63) wsum[wv] = s;
        __syncthreads();
        if (wv == 0) {
            int ws = (lane < 16) ? wsum[lane] : 0;
            #pragma unroll
            for (int off = 1; off < 16; off <<= 1) {
                int u = __shfl_up(ws, off, 64);
                if (lane >= off) ws += u;
            }
            if (lane < 16) wsum[lane] = ws;
        }
        __syncthreads();
        int wave_off = (wv == 0) ? 0 : wsum[wv - 1];
        int incl = carry + wave_off + s;
        if (i < n) row_ptr[i + 1] = incl;
        __syncthreads();
        if (tid == 1023) carry = incl;
        __syncthreads();
    }
    if (tid == 0) row_ptr[0] = 0;
}

__global__ void copy_int_kernel(const int* __restrict__ a, int* __restrict__ b, int n) {
    int i = blockIdx.x * blockDim.x + threadIdx.x;
    if (i < n) b[i] = a[i];
}

__global__ void scatter_kernel(const int* __restrict__ src, const int* __restrict__ dst,
                               const float* __restrict__ w, int* __restrict__ pos,
                               int* __restrict__ csr_dst, float* __restrict__ csr_w, int E) {
    int e = blockIdx.x * blockDim.x + threadIdx.x;
    if (e < E) {
        int r = src[e];
        int p = atomicAdd(&pos[r], 1);
        csr_dst[p] = dst[e];
        csr_w[p]  = w[e];
    }
}

// ---------------- diffusion ----------------

__global__ void init_kernel(const float4* __restrict__ x, float4* __restrict__ term,
                            float4* __restrict__ acc, int n4) {
    int i = blockIdx.x * blockDim.x + threadIdx.x;
    if (i < n4) { float4 v = x[i]; term[i] = v; acc[i] = v; }
}

__global__ void copy4_kernel(const float4* __restrict__ a, float4* __restrict__ b, int n4) {
    int i = blockIdx.x * blockDim.x + threadIdx.x;
    if (i < n4) b[i] = a[i];
}

// one wave per row, lane = channel
__global__ void taylor_kernel(const int* __restrict__ row_ptr, const int* __restrict__ csr_dst,
                              const float* __restrict__ csr_w,
                              const float* __restrict__ term_in, float* __restrict__ term_out,
                              float* __restrict__ acc, const float* __restrict__ t_ptr,
                              float inv_k, int n) {
    int wid = (blockIdx.x * blockDim.x + threadIdx.x) >> 6;
    int lane = threadIdx.x & 63;
    if (wid >= n) return;
    float t = t_ptr[0];
    t = fmaxf(t, 1e-8f);
    float coef = -(t * (1.0f / N_SUB)) * inv_k;
    int beg = row_ptr[wid];
    int end = row_ptr[wid + 1];
    float sum = 0.0f;
    for (int e = beg; e < end; ++e) {
        int d = csr_dst[e];
        float w = csr_w[e];
        sum += w * term_in[d * C_CH + lane];
    }
    float val = coef * sum;
    int idx = wid * C_CH + lane;
    term_out[idx] = val;
    acc[idx] += val;
}

extern "C" void kernel_launch(void* const* d_in, const int* in_sizes, int n_in,
                              void* d_out, int out_size, void* d_ws, size_t ws_size,
                              hipStream_t stream) {
    const float* x    = (const float*)d_in[0];
    const int*   esrc = (const int*)d_in[1];
    const int*   edst = (const int*)d_in[2];
    const float* ew   = (const float*)d_in[3];
    const float* tp   = (const float*)d_in[4];
    float* out = (float*)d_out;

    const int E = in_sizes[1];
    const int N = N_NODES;
    const int n4 = N * C_CH / 4;

    int* ws = (int*)d_ws;
    int* row_ptr = ws;                         // N+1 (padded slot 50004)
    int* row_cnt = ws + 50004;                 // N   (50000)
    int* csr_dst = ws + 100004;                // E
    float* csr_w = (float*)(ws + 100004 + E);  // E
    float* term_a = (float*)(ws + 100004 + 2 * E);   // N*C
    float* term_b = term_a + (size_t)N * C_CH;       // N*C

    // CSR build
    hipMemsetAsync(row_cnt, 0, (size_t)N * sizeof(int), stream);
    hist_kernel<<<(E + 255) / 256, 256, 0, stream>>>(esrc, row_cnt, E);
    scan_kernel<<<1, 1024, 0, stream>>>(row_cnt, row_ptr, N);
    copy_int_kernel<<<(N + 255) / 256, 256, 0, stream>>>(row_ptr, row_cnt, N);
    scatter_kernel<<<(E + 255) / 256, 256, 0, stream>>>(esrc, edst, ew, row_cnt,
                                                        csr_dst, csr_w, E);

    // acc = x, term_a = x
    init_kernel<<<(n4 + 255) / 256, 256, 0, stream>>>((const float4*)x,
                                                      (float4*)term_a, (float4*)out, n4);

    const int rows_per_block = 256 / 64;
    const int tgrid = (N + rows_per_block - 1) / rows_per_block;

    const float* tin = term_a;
    float* tout = term_b;
    for (int s = 0; s < N_SUB; ++s) {
        if (s > 0) {
            // term_a = acc
            copy4_kernel<<<(n4 + 255) / 256, 256, 0, stream>>>((const float4*)out,
                                                               (float4*)term_a, n4);
            tin = term_a;
            tout = term_b;
        }
        for (int k = 1; k <= M_TERMS; ++k) {
            taylor_kernel<<<tgrid, 256, 0, stream>>>(row_ptr, csr_dst, csr_w,
                                                     tin, tout, out, tp,
                                                     1.0f / (float)k, N);
            const float* tmp = tin;
            tin = tout;
            tout = (float*)tmp;
        }
    }
}

// Round 2
// 1601.217 us; speedup vs baseline: 4.2888x; 4.2888x over previous
//
#include <hip/hip_runtime.h>

#define N_NODES 50000
#define C_CH 64
#define N_SUB 4
#define M_TERMS 8   // terms beyond 8 are < 1e-12 of output (||A||<=0.12) — below fp32 ulp

// ---------------- CSR build ----------------

__global__ void hist_kernel(const int* __restrict__ src, int* __restrict__ cnt, int E) {
    int e = blockIdx.x * blockDim.x + threadIdx.x;
    if (e < E) atomicAdd(&cnt[src[e]], 1);
}

// single-block exclusive scan over n counts -> row_ptr[0..n]
__global__ void scan_kernel(const int* __restrict__ cnt, int* __restrict__ row_ptr, int n) {
    __shared__ int wsum[16];
    __shared__ int carry;
    const int tid = threadIdx.x;
    const int lane = tid & 63;
    const int wv = tid >> 6;
    if (tid == 0) carry = 0;
    __syncthreads();
    for (int base = 0; base < n; base += 1024) {
        int i = base + tid;
        int v = (i < n) ? cnt[i] : 0;
        int s = v;
        #pragma unroll
        for (int off = 1; off < 64; off <<= 1) {
            int u = __shfl_up(s, off, 64);
            if (lane >= off) s += u;
        }
        if (lane == 63) wsum[wv] = s;
        __syncthreads();
        if (wv == 0) {
            int ws = (lane < 16) ? wsum[lane] : 0;
            #pragma unroll
            for (int off = 1; off < 16; off <<= 1) {
                int u = __shfl_up(ws, off, 64);
                if (lane >= off) ws += u;
            }
            if (lane < 16) wsum[lane] = ws;
        }
        __syncthreads();
        int wave_off = (wv == 0) ? 0 : wsum[wv - 1];
        int incl = carry + wave_off + s;
        if (i < n) row_ptr[i + 1] = incl;
        __syncthreads();
        if (tid == 1023) carry = incl;
        __syncthreads();
    }
    if (tid == 0) row_ptr[0] = 0;
}

__global__ void copy_int_kernel(const int* __restrict__ a, int* __restrict__ b, int n) {
    int i = blockIdx.x * blockDim.x + threadIdx.x;
    if (i < n) b[i] = a[i];
}

__global__ void scatter_kernel(const int* __restrict__ src, const int* __restrict__ dst,
                               const float* __restrict__ w, int* __restrict__ pos,
                               int* __restrict__ csr_dst, float* __restrict__ csr_w, int E) {
    int e = blockIdx.x * blockDim.x + threadIdx.x;
    if (e < E) {
        int r = src[e];
        int p = atomicAdd(&pos[r], 1);
        csr_dst[p] = dst[e];
        csr_w[p]  = w[e];
    }
}

// ---------------- diffusion ----------------

__global__ void init_kernel(const float4* __restrict__ x, float4* __restrict__ term,
                            float4* __restrict__ acc, int n4) {
    int i = blockIdx.x * blockDim.x + threadIdx.x;
    if (i < n4) { float4 v = x[i]; term[i] = v; acc[i] = v; }
}

__global__ void copy4_kernel(const float4* __restrict__ a, float4* __restrict__ b, int n4) {
    int i = blockIdx.x * blockDim.x + threadIdx.x;
    if (i < n4) b[i] = a[i];
}

// one wave per row, lane = channel; edge loop unrolled x4 for memory concurrency
__global__ __launch_bounds__(256) void
taylor_kernel(const int* __restrict__ row_ptr, const int* __restrict__ csr_dst,
              const float* __restrict__ csr_w,
              const float* __restrict__ term_in, float* __restrict__ term_out,
              float* __restrict__ acc, const float* __restrict__ t_ptr,
              float inv_k, int n) {
    int wid = (blockIdx.x * blockDim.x + threadIdx.x) >> 6;
    int lane = threadIdx.x & 63;
    if (wid >= n) return;
    float t = t_ptr[0];
    t = fmaxf(t, 1e-8f);
    float coef = -(t * (1.0f / N_SUB)) * inv_k;
    int beg = row_ptr[wid];
    int end = row_ptr[wid + 1];

    float s0 = 0.0f, s1 = 0.0f, s2 = 0.0f, s3 = 0.0f;
    int e = beg;
    for (; e + 4 <= end; e += 4) {
        int d0 = csr_dst[e + 0];
        int d1 = csr_dst[e + 1];
        int d2 = csr_dst[e + 2];
        int d3 = csr_dst[e + 3];
        float w0 = csr_w[e + 0];
        float w1 = csr_w[e + 1];
        float w2 = csr_w[e + 2];
        float w3 = csr_w[e + 3];
        float v0 = term_in[(size_t)d0 * C_CH + lane];
        float v1 = term_in[(size_t)d1 * C_CH + lane];
        float v2 = term_in[(size_t)d2 * C_CH + lane];
        float v3 = term_in[(size_t)d3 * C_CH + lane];
        s0 = fmaf(w0, v0, s0);
        s1 = fmaf(w1, v1, s1);
        s2 = fmaf(w2, v2, s2);
        s3 = fmaf(w3, v3, s3);
    }
    for (; e < end; ++e) {
        s0 = fmaf(csr_w[e], term_in[(size_t)csr_dst[e] * C_CH + lane], s0);
    }
    float val = coef * ((s0 + s1) + (s2 + s3));
    int idx = wid * C_CH + lane;
    term_out[idx] = val;
    acc[idx] += val;
}

extern "C" void kernel_launch(void* const* d_in, const int* in_sizes, int n_in,
                              void* d_out, int out_size, void* d_ws, size_t ws_size,
                              hipStream_t stream) {
    const float* x    = (const float*)d_in[0];
    const int*   esrc = (const int*)d_in[1];
    const int*   edst = (const int*)d_in[2];
    const float* ew   = (const float*)d_in[3];
    const float* tp   = (const float*)d_in[4];
    float* out = (float*)d_out;

    const int E = in_sizes[1];
    const int N = N_NODES;
    const int n4 = N * C_CH / 4;

    int* ws = (int*)d_ws;
    int* row_ptr = ws;                         // N+1 (padded slot 50004)
    int* row_cnt = ws + 50004;                 // N   (50000)
    int* csr_dst = ws + 100004;                // E
    float* csr_w = (float*)(ws + 100004 + E);  // E
    float* term_a = (float*)(ws + 100004 + 2 * E);   // N*C
    float* term_b = term_a + (size_t)N * C_CH;       // N*C

    // CSR build
    hipMemsetAsync(row_cnt, 0, (size_t)N * sizeof(int), stream);
    hist_kernel<<<(E + 255) / 256, 256, 0, stream>>>(esrc, row_cnt, E);
    scan_kernel<<<1, 1024, 0, stream>>>(row_cnt, row_ptr, N);
    copy_int_kernel<<<(N + 255) / 256, 256, 0, stream>>>(row_ptr, row_cnt, N);
    scatter_kernel<<<(E + 255) / 256, 256, 0, stream>>>(esrc, edst, ew, row_cnt,
                                                        csr_dst, csr_w, E);

    // acc = x, term_a = x
    init_kernel<<<(n4 + 255) / 256, 256, 0, stream>>>((const float4*)x,
                                                      (float4*)term_a, (float4*)out, n4);

    const int rows_per_block = 256 / 64;
    const int tgrid = (N + rows_per_block - 1) / rows_per_block;

    const float* tin = term_a;
    float* tout = term_b;
    for (int s = 0; s < N_SUB; ++s) {
        if (s > 0) {
            // term_a = acc (fresh substep input)
            copy4_kernel<<<(n4 + 255) / 256, 256, 0, stream>>>((const float4*)out,
                                                               (float4*)term_a, n4);
            tin = term_a;
            tout = term_b;
        }
        for (int k = 1; k <= M_TERMS; ++k) {
            taylor_kernel<<<tgrid, 256, 0, stream>>>(row_ptr, csr_dst, csr_w,
                                                     tin, tout, out, tp,
                                                     1.0f / (float)k, N);
            const float* tmp = tin;
            tin = tout;
            tout = (float*)tmp;
        }
    }
}

// Round 3
// 525.679 us; speedup vs baseline: 13.0637x; 3.0460x over previous
//
#include <hip/hip_runtime.h>

#define N_NODES 50000
#define C_CH 64
#define M_TERMS 12  // single substep: ||-t*L||inf <= ~0.6 (<=1.0 worst case);
                    // remainder after 12 terms < 2e-10 — below fp32 ulp

// ---------------- CSR build ----------------

__global__ void hist_kernel(const int* __restrict__ src, int* __restrict__ cnt, int E) {
    int e = blockIdx.x * blockDim.x + threadIdx.x;
    if (e < E) atomicAdd(&cnt[src[e]], 1);
}

// pass 1: per-block (1024) inclusive scan -> row_ptr[i+1]; block totals -> blk_sum
__global__ void scan1_kernel(const int* __restrict__ cnt, int* __restrict__ row_ptr,
                             int* __restrict__ blk_sum, int n) {
    __shared__ int wsum[16];
    const int tid = threadIdx.x;
    const int lane = tid & 63;
    const int wv = tid >> 6;
    int i = blockIdx.x * 1024 + tid;
    int v = (i < n) ? cnt[i] : 0;
    int s = v;
    #pragma unroll
    for (int off = 1; off < 64; off <<= 1) {
        int u = __shfl_up(s, off, 64);
        if (lane >= off) s += u;
    }
    if (lane == 63) wsum[wv] = s;
    __syncthreads();
    if (wv == 0) {
        int ws = (lane < 16) ? wsum[lane] : 0;
        #pragma unroll
        for (int off = 1; off < 16; off <<= 1) {
            int u = __shfl_up(ws, off, 64);
            if (lane >= off) ws += u;
        }
        if (lane < 16) wsum[lane] = ws;
    }
    __syncthreads();
    int incl = s + ((wv == 0) ? 0 : wsum[wv - 1]);
    if (i < n) row_ptr[i + 1] = incl;
    if (tid == 1023) blk_sum[blockIdx.x] = incl;
}

// pass 2: single wave scans <=64 block sums -> exclusive offsets in place
__global__ void scan2_kernel(int* __restrict__ blk_sum, int nb) {
    int lane = threadIdx.x;
    int v = (lane < nb) ? blk_sum[lane] : 0;
    int s = v;
    #pragma unroll
    for (int off = 1; off < 64; off <<= 1) {
        int u = __shfl_up(s, off, 64);
        if (lane >= off) s += u;
    }
    if (lane < nb) blk_sum[lane] = s - v;  // exclusive
}

// pass 3: add block offsets; emit scatter cursors pos[i] = exclusive prefix
__global__ void scan3_kernel(int* __restrict__ row_ptr, int* __restrict__ pos,
                             const int* __restrict__ blk_sum, const int* __restrict__ cnt,
                             int n) {
    int i = blockIdx.x * blockDim.x + threadIdx.x;
    if (i < n) {
        int incl = row_ptr[i + 1] + blk_sum[i >> 10];
        row_ptr[i + 1] = incl;
        pos[i] = incl - cnt[i];
    }
    if (i == 0) row_ptr[0] = 0;
}

__global__ void scatter_kernel(const int* __restrict__ src, const int* __restrict__ dst,
                               const float* __restrict__ w, int* __restrict__ pos,
                               int2* __restrict__ csr, int E) {
    int e = blockIdx.x * blockDim.x + threadIdx.x;
    if (e < E) {
        int r = src[e];
        int p = atomicAdd(&pos[r], 1);
        csr[p] = make_int2(dst[e], __float_as_int(w[e]));
    }
}

// ---------------- diffusion ----------------
// one wave per row, lane = channel; 8 gathers in flight per wave

__global__ __launch_bounds__(256) void
taylor_kernel(const int* __restrict__ row_ptr, const int2* __restrict__ csr,
              const float* __restrict__ term_in, float* __restrict__ term_out,
              float* __restrict__ acc, const float* __restrict__ t_ptr,
              float inv_k, int n, int first) {
    int wid = (blockIdx.x * blockDim.x + threadIdx.x) >> 6;
    int lane = threadIdx.x & 63;
    if (wid >= n) return;
    float t = fmaxf(t_ptr[0], 1e-8f);
    float coef = -t * inv_k;
    int beg = row_ptr[wid];
    int end = row_ptr[wid + 1];

    float s0 = 0.0f, s1 = 0.0f, s2 = 0.0f, s3 = 0.0f;
    int e = beg;
    for (; e + 8 <= end; e += 8) {
        int2 m0 = csr[e + 0], m1 = csr[e + 1], m2 = csr[e + 2], m3 = csr[e + 3];
        int2 m4 = csr[e + 4], m5 = csr[e + 5], m6 = csr[e + 6], m7 = csr[e + 7];
        float v0 = term_in[(size_t)m0.x * C_CH + lane];
        float v1 = term_in[(size_t)m1.x * C_CH + lane];
        float v2 = term_in[(size_t)m2.x * C_CH + lane];
        float v3 = term_in[(size_t)m3.x * C_CH + lane];
        float v4 = term_in[(size_t)m4.x * C_CH + lane];
        float v5 = term_in[(size_t)m5.x * C_CH + lane];
        float v6 = term_in[(size_t)m6.x * C_CH + lane];
        float v7 = term_in[(size_t)m7.x * C_CH + lane];
        s0 = fmaf(__int_as_float(m0.y), v0, s0);
        s1 = fmaf(__int_as_float(m1.y), v1, s1);
        s2 = fmaf(__int_as_float(m2.y), v2, s2);
        s3 = fmaf(__int_as_float(m3.y), v3, s3);
        s0 = fmaf(__int_as_float(m4.y), v4, s0);
        s1 = fmaf(__int_as_float(m5.y), v5, s1);
        s2 = fmaf(__int_as_float(m6.y), v6, s2);
        s3 = fmaf(__int_as_float(m7.y), v7, s3);
    }
    for (; e + 2 <= end; e += 2) {
        int2 m0 = csr[e + 0], m1 = csr[e + 1];
        float v0 = term_in[(size_t)m0.x * C_CH + lane];
        float v1 = term_in[(size_t)m1.x * C_CH + lane];
        s0 = fmaf(__int_as_float(m0.y), v0, s0);
        s1 = fmaf(__int_as_float(m1.y), v1, s1);
    }
    if (e < end) {
        int2 m0 = csr[e];
        s2 = fmaf(__int_as_float(m0.y), term_in[(size_t)m0.x * C_CH + lane], s2);
    }
    float val = coef * ((s0 + s1) + (s2 + s3));
    size_t idx = (size_t)wid * C_CH + lane;
    term_out[idx] = val;
    if (first) acc[idx] = term_in[idx] + val;  // term_in == x on the first step
    else       acc[idx] += val;
}

extern "C" void kernel_launch(void* const* d_in, const int* in_sizes, int n_in,
                              void* d_out, int out_size, void* d_ws, size_t ws_size,
                              hipStream_t stream) {
    const float* x    = (const float*)d_in[0];
    const int*   esrc = (const int*)d_in[1];
    const int*   edst = (const int*)d_in[2];
    const float* ew   = (const float*)d_in[3];
    const float* tp   = (const float*)d_in[4];
    float* out = (float*)d_out;

    const int E = in_sizes[1];
    const int N = N_NODES;

    int* ws = (int*)d_ws;
    int* row_ptr = ws;                          // N+1, pad to 50008
    int* cnt     = ws + 50008;                  // N
    int* pos     = ws + 100008;                 // N
    int* blk_sum = ws + 150008;                 // 64, pad to 150080
    int2* csr    = (int2*)(ws + 150080);        // E int2 (byte off 600320, 8-aligned)
    float* term_a = (float*)(ws + 150080 + 2 * E);       // N*C
    float* term_b = term_a + (size_t)N * C_CH;           // N*C

    // CSR build
    hipMemsetAsync(cnt, 0, (size_t)N * sizeof(int), stream);
    hist_kernel<<<(E + 255) / 256, 256, 0, stream>>>(esrc, cnt, E);
    const int nb = (N + 1023) / 1024;  // 49
    scan1_kernel<<<nb, 1024, 0, stream>>>(cnt, row_ptr, blk_sum, N);
    scan2_kernel<<<1, 64, 0, stream>>>(blk_sum, nb);
    scan3_kernel<<<(N + 255) / 256, 256, 0, stream>>>(row_ptr, pos, blk_sum, cnt, N);
    scatter_kernel<<<(E + 255) / 256, 256, 0, stream>>>(esrc, edst, ew, pos, csr, E);

    const int rows_per_block = 256 / 64;
    const int tgrid = (N + rows_per_block - 1) / rows_per_block;

    // k=1 reads x directly, seeds acc = x + term1
    taylor_kernel<<<tgrid, 256, 0, stream>>>(row_ptr, csr, x, term_b, out, tp,
                                             1.0f, N, 1);
    const float* tin = term_b;
    float* tout = term_a;
    for (int k = 2; k <= M_TERMS; ++k) {
        taylor_kernel<<<tgrid, 256, 0, stream>>>(row_ptr, csr, tin, tout, out, tp,
                                                 1.0f / (float)k, N, 0);
        const float* tmp = tin;
        tin = tout;
        tout = (float*)tmp;
    }
}

// Round 4
// 386.119 us; speedup vs baseline: 17.7855x; 1.3614x over previous
//
#include <hip/hip_runtime.h>

#define N_NODES 50000
#define C_CH 64
#define M_TERMS 9   // ||-t*L||inf <= ~1.0 worst case; tail after 9 terms < 3e-7

typedef unsigned short ushort_t;
typedef unsigned int uint_t;

__device__ __forceinline__ float bf2f(ushort_t h) {
    return __uint_as_float(((uint_t)h) << 16);
}
__device__ __forceinline__ ushort_t f2bf(float f) {  // round-to-nearest-even
    uint_t u = __float_as_uint(f);
    u += 0x7FFFu + ((u >> 16) & 1u);
    return (ushort_t)(u >> 16);
}

// ---------------- CSR build ----------------

__global__ void hist_kernel(const int* __restrict__ src, int* __restrict__ cnt, int E) {
    int e = blockIdx.x * blockDim.x + threadIdx.x;
    if (e < E) atomicAdd(&cnt[src[e]], 1);
}

// pass 1: per-block (1024) inclusive scan -> row_ptr[i+1]; block totals -> blk_sum
__global__ void scan1_kernel(const int* __restrict__ cnt, int* __restrict__ row_ptr,
                             int* __restrict__ blk_sum, int n) {
    __shared__ int wsum[16];
    const int tid = threadIdx.x;
    const int lane = tid & 63;
    const int wv = tid >> 6;
    int i = blockIdx.x * 1024 + tid;
    int v = (i < n) ? cnt[i] : 0;
    int s = v;
    #pragma unroll
    for (int off = 1; off < 64; off <<= 1) {
        int u = __shfl_up(s, off, 64);
        if (lane >= off) s += u;
    }
    if (lane == 63) wsum[wv] = s;
    __syncthreads();
    if (wv == 0) {
        int ws = (lane < 16) ? wsum[lane] : 0;
        #pragma unroll
        for (int off = 1; off < 16; off <<= 1) {
            int u = __shfl_up(ws, off, 64);
            if (lane >= off) ws += u;
        }
        if (lane < 16) wsum[lane] = ws;
    }
    __syncthreads();
    int incl = s + ((wv == 0) ? 0 : wsum[wv - 1]);
    if (i < n) row_ptr[i + 1] = incl;
    if (tid == 1023) blk_sum[blockIdx.x] = incl;
}

// pass 2: single wave scans <=64 block sums -> exclusive offsets in place
__global__ void scan2_kernel(int* __restrict__ blk_sum, int nb) {
    int lane = threadIdx.x;
    int v = (lane < nb) ? blk_sum[lane] : 0;
    int s = v;
    #pragma unroll
    for (int off = 1; off < 64; off <<= 1) {
        int u = __shfl_up(s, off, 64);
        if (lane >= off) s += u;
    }
    if (lane < nb) blk_sum[lane] = s - v;  // exclusive
}

// pass 3: add block offsets; emit scatter cursors pos[i] = exclusive prefix
__global__ void scan3_kernel(int* __restrict__ row_ptr, int* __restrict__ pos,
                             const int* __restrict__ blk_sum, const int* __restrict__ cnt,
                             int n) {
    int i = blockIdx.x * blockDim.x + threadIdx.x;
    if (i < n) {
        int incl = row_ptr[i + 1] + blk_sum[i >> 10];
        row_ptr[i + 1] = incl;
        pos[i] = incl - cnt[i];
    }
    if (i == 0) row_ptr[0] = 0;
}

__global__ void scatter_kernel(const int* __restrict__ src, const int* __restrict__ dst,
                               const float* __restrict__ w, int* __restrict__ pos,
                               int2* __restrict__ csr, int E) {
    int e = blockIdx.x * blockDim.x + threadIdx.x;
    if (e < E) {
        int r = src[e];
        int p = atomicAdd(&pos[r], 1);
        csr[p] = make_int2(dst[e], __float_as_int(w[e]));
    }
}

// x (fp32) -> xb (bf16); 2 elems/thread
__global__ void cvt_kernel(const float2* __restrict__ x, uint_t* __restrict__ xb, int n2) {
    int i = blockIdx.x * blockDim.x + threadIdx.x;
    if (i < n2) {
        float2 v = x[i];
        xb[i] = (uint_t)f2bf(v.x) | ((uint_t)f2bf(v.y) << 16);
    }
}

// ---------------- diffusion ----------------
// one wave per row, lane = channel; bf16 gather (128B/edge), 8 in flight

__global__ __launch_bounds__(256) void
taylor_kernel(const int* __restrict__ row_ptr, const int2* __restrict__ csr,
              const ushort_t* __restrict__ term_in, ushort_t* __restrict__ term_out,
              float* __restrict__ acc, const float* __restrict__ x,
              const float* __restrict__ t_ptr,
              float inv_k, int n, int first) {
    int wid = (blockIdx.x * blockDim.x + threadIdx.x) >> 6;
    int lane = threadIdx.x & 63;
    if (wid >= n) return;
    float t = fmaxf(t_ptr[0], 1e-8f);
    float coef = -t * inv_k;
    int beg = row_ptr[wid];
    int end = row_ptr[wid + 1];

    float s0 = 0.0f, s1 = 0.0f, s2 = 0.0f, s3 = 0.0f;
    int e = beg;
    for (; e + 8 <= end; e += 8) {
        int2 m0 = csr[e + 0], m1 = csr[e + 1], m2 = csr[e + 2], m3 = csr[e + 3];
        int2 m4 = csr[e + 4], m5 = csr[e + 5], m6 = csr[e + 6], m7 = csr[e + 7];
        float v0 = bf2f(term_in[(size_t)m0.x * C_CH + lane]);
        float v1 = bf2f(term_in[(size_t)m1.x * C_CH + lane]);
        float v2 = bf2f(term_in[(size_t)m2.x * C_CH + lane]);
        float v3 = bf2f(term_in[(size_t)m3.x * C_CH + lane]);
        float v4 = bf2f(term_in[(size_t)m4.x * C_CH + lane]);
        float v5 = bf2f(term_in[(size_t)m5.x * C_CH + lane]);
        float v6 = bf2f(term_in[(size_t)m6.x * C_CH + lane]);
        float v7 = bf2f(term_in[(size_t)m7.x * C_CH + lane]);
        s0 = fmaf(__int_as_float(m0.y), v0, s0);
        s1 = fmaf(__int_as_float(m1.y), v1, s1);
        s2 = fmaf(__int_as_float(m2.y), v2, s2);
        s3 = fmaf(__int_as_float(m3.y), v3, s3);
        s0 = fmaf(__int_as_float(m4.y), v4, s0);
        s1 = fmaf(__int_as_float(m5.y), v5, s1);
        s2 = fmaf(__int_as_float(m6.y), v6, s2);
        s3 = fmaf(__int_as_float(m7.y), v7, s3);
    }
    for (; e + 4 <= end; e += 4) {
        int2 m0 = csr[e + 0], m1 = csr[e + 1], m2 = csr[e + 2], m3 = csr[e + 3];
        float v0 = bf2f(term_in[(size_t)m0.x * C_CH + lane]);
        float v1 = bf2f(term_in[(size_t)m1.x * C_CH + lane]);
        float v2 = bf2f(term_in[(size_t)m2.x * C_CH + lane]);
        float v3 = bf2f(term_in[(size_t)m3.x * C_CH + lane]);
        s0 = fmaf(__int_as_float(m0.y), v0, s0);
        s1 = fmaf(__int_as_float(m1.y), v1, s1);
        s2 = fmaf(__int_as_float(m2.y), v2, s2);
        s3 = fmaf(__int_as_float(m3.y), v3, s3);
    }
    for (; e < end; ++e) {
        int2 m0 = csr[e];
        s0 = fmaf(__int_as_float(m0.y), bf2f(term_in[(size_t)m0.x * C_CH + lane]), s0);
    }
    float val = coef * ((s0 + s1) + (s2 + s3));
    size_t idx = (size_t)wid * C_CH + lane;
    term_out[idx] = f2bf(val);
    if (first) acc[idx] = x[idx] + val;  // seed acc from fp32 x (exact)
    else       acc[idx] += val;
}

extern "C" void kernel_launch(void* const* d_in, const int* in_sizes, int n_in,
                              void* d_out, int out_size, void* d_ws, size_t ws_size,
                              hipStream_t stream) {
    const float* x    = (const float*)d_in[0];
    const int*   esrc = (const int*)d_in[1];
    const int*   edst = (const int*)d_in[2];
    const float* ew   = (const float*)d_in[3];
    const float* tp   = (const float*)d_in[4];
    float* out = (float*)d_out;

    const int E = in_sizes[1];
    const int N = N_NODES;
    const int NC = N * C_CH;

    int* ws = (int*)d_ws;
    int* row_ptr = ws;                          // N+1, pad to 50008
    int* cnt     = ws + 50008;                  // N
    int* pos     = ws + 100008;                 // N
    int* blk_sum = ws + 150008;                 // 64, pad to 150080
    int2* csr    = (int2*)(ws + 150080);        // E int2
    ushort_t* xb     = (ushort_t*)(ws + 150080 + 2 * E);  // N*C bf16
    ushort_t* term_a = xb + (size_t)NC;                   // N*C bf16
    ushort_t* term_b = term_a + (size_t)NC;               // N*C bf16

    // CSR build
    hipMemsetAsync(cnt, 0, (size_t)N * sizeof(int), stream);
    hist_kernel<<<(E + 255) / 256, 256, 0, stream>>>(esrc, cnt, E);
    const int nb = (N + 1023) / 1024;  // 49
    scan1_kernel<<<nb, 1024, 0, stream>>>(cnt, row_ptr, blk_sum, N);
    scan2_kernel<<<1, 64, 0, stream>>>(blk_sum, nb);
    scan3_kernel<<<(N + 255) / 256, 256, 0, stream>>>(row_ptr, pos, blk_sum, cnt, N);
    scatter_kernel<<<(E + 255) / 256, 256, 0, stream>>>(esrc, edst, ew, pos, csr, E);

    // x -> bf16
    cvt_kernel<<<(NC / 2 + 255) / 256, 256, 0, stream>>>((const float2*)x,
                                                         (uint_t*)xb, NC / 2);

    const int rows_per_block = 256 / 64;
    const int tgrid = (N + rows_per_block - 1) / rows_per_block;

    // k=1 gathers xb, seeds acc = x + term1
    taylor_kernel<<<tgrid, 256, 0, stream>>>(row_ptr, csr, xb, term_b, out, x, tp,
                                             1.0f, N, 1);
    const ushort_t* tin = term_b;
    ushort_t* tout = term_a;
    for (int k = 2; k <= M_TERMS; ++k) {
        taylor_kernel<<<tgrid, 256, 0, stream>>>(row_ptr, csr, tin, tout, out, x, tp,
                                                 1.0f / (float)k, N, 0);
        const ushort_t* tmp = tin;
        tin = tout;
        tout = (ushort_t*)tmp;
    }
}

// Round 5
// 310.799 us; speedup vs baseline: 22.0957x; 1.2423x over previous
//
#include <hip/hip_runtime.h>

#define N_NODES 50000
#define C_CH 64
#define M_TERMS 8   // ||-t*L||inf <= ~1.0 worst case; tail after 8 terms < 3e-6

typedef unsigned short ushort_t;
typedef unsigned int uint_t;

__device__ __forceinline__ float bf2f(uint_t h16) {  // low 16 bits = bf16
    return __uint_as_float(h16 << 16);
}
__device__ __forceinline__ ushort_t f2bf(float f) {  // round-to-nearest-even
    uint_t u = __float_as_uint(f);
    u += 0x7FFFu + ((u >> 16) & 1u);
    return (ushort_t)(u >> 16);
}

// ---------------- CSR build ----------------

__global__ void hist_kernel(const int* __restrict__ src, int* __restrict__ cnt, int E) {
    int e = blockIdx.x * blockDim.x + threadIdx.x;
    if (e < E) atomicAdd(&cnt[src[e]], 1);
}

// pass 1: per-block (1024) inclusive scan -> row_ptr[i+1]; block totals -> blk_sum
__global__ void scan1_kernel(const int* __restrict__ cnt, int* __restrict__ row_ptr,
                             int* __restrict__ blk_sum, int n) {
    __shared__ int wsum[16];
    const int tid = threadIdx.x;
    const int lane = tid & 63;
    const int wv = tid >> 6;
    int i = blockIdx.x * 1024 + tid;
    int v = (i < n) ? cnt[i] : 0;
    int s = v;
    #pragma unroll
    for (int off = 1; off < 64; off <<= 1) {
        int u = __shfl_up(s, off, 64);
        if (lane >= off) s += u;
    }
    if (lane == 63) wsum[wv] = s;
    __syncthreads();
    if (wv == 0) {
        int ws = (lane < 16) ? wsum[lane] : 0;
        #pragma unroll
        for (int off = 1; off < 16; off <<= 1) {
            int u = __shfl_up(ws, off, 64);
            if (lane >= off) ws += u;
        }
        if (lane < 16) wsum[lane] = ws;
    }
    __syncthreads();
    int incl = s + ((wv == 0) ? 0 : wsum[wv - 1]);
    if (i < n) row_ptr[i + 1] = incl;
    if (tid == 1023) blk_sum[blockIdx.x] = incl;
}

// pass 2: single wave scans <=64 block sums -> exclusive offsets in place
__global__ void scan2_kernel(int* __restrict__ blk_sum, int nb) {
    int lane = threadIdx.x;
    int v = (lane < nb) ? blk_sum[lane] : 0;
    int s = v;
    #pragma unroll
    for (int off = 1; off < 64; off <<= 1) {
        int u = __shfl_up(s, off, 64);
        if (lane >= off) s += u;
    }
    if (lane < nb) blk_sum[lane] = s - v;  // exclusive
}

// pass 3: add block offsets; emit scatter cursors pos[i] = exclusive prefix
__global__ void scan3_kernel(int* __restrict__ row_ptr, int* __restrict__ pos,
                             const int* __restrict__ blk_sum, const int* __restrict__ cnt,
                             int n) {
    int i = blockIdx.x * blockDim.x + threadIdx.x;
    if (i < n) {
        int incl = row_ptr[i + 1] + blk_sum[i >> 10];
        row_ptr[i + 1] = incl;
        pos[i] = incl - cnt[i];
    }
    if (i == 0) row_ptr[0] = 0;
}

// packed CSR entry: low16 = dst (N<65536), high16 = bf16(w)
__global__ void scatter_kernel(const int* __restrict__ src, const int* __restrict__ dst,
                               const float* __restrict__ w, int* __restrict__ pos,
                               uint_t* __restrict__ csr, int E) {
    int e = blockIdx.x * blockDim.x + threadIdx.x;
    if (e < E) {
        int r = src[e];
        int p = atomicAdd(&pos[r], 1);
        csr[p] = (uint_t)dst[e] | ((uint_t)f2bf(w[e]) << 16);
    }
}

// x (fp32) -> xb (bf16x2 packed); 2 elems/thread
__global__ void cvt_kernel(const float2* __restrict__ x, uint_t* __restrict__ xb, int n2) {
    int i = blockIdx.x * blockDim.x + threadIdx.x;
    if (i < n2) {
        float2 v = x[i];
        xb[i] = (uint_t)f2bf(v.x) | ((uint_t)f2bf(v.y) << 16);
    }
}

// ---------------- diffusion ----------------
// HALF-wave per row: 32 lanes x (bf16x2) = 128B row; 2 rows/wave, 8-deep unroll
// -> 16 outstanding gathers per wave.

#define EDGE_BODY(M, SA, SB)                                     \
    {                                                            \
        uint_t _m = (M);                                         \
        float _w = bf2f(_m >> 16);                               \
        uint_t _v = term_in[(size_t)(_m & 0xFFFFu) * 32 + lane]; \
        SA = fmaf(_w, bf2f(_v & 0xFFFFu), SA);                   \
        SB = fmaf(_w, bf2f(_v >> 16), SB);                       \
    }

__global__ __launch_bounds__(256) void
taylor_kernel(const int* __restrict__ row_ptr, const uint_t* __restrict__ csr,
              const uint_t* __restrict__ term_in, uint_t* __restrict__ term_out,
              float2* __restrict__ acc, const float2* __restrict__ x,
              const float* __restrict__ t_ptr,
              float inv_k, int n, int first) {
    int row = (blockIdx.x * blockDim.x + threadIdx.x) >> 5;
    int lane = threadIdx.x & 31;
    if (row >= n) return;
    float t = fmaxf(t_ptr[0], 1e-8f);
    float coef = -t * inv_k;
    int beg = row_ptr[row];
    int end = row_ptr[row + 1];

    float a0 = 0.f, a1 = 0.f, a2 = 0.f, a3 = 0.f;
    float b0 = 0.f, b1 = 0.f, b2 = 0.f, b3 = 0.f;
    int e = beg;
    for (; e + 8 <= end; e += 8) {
        uint_t m0 = csr[e + 0], m1 = csr[e + 1], m2 = csr[e + 2], m3 = csr[e + 3];
        uint_t m4 = csr[e + 4], m5 = csr[e + 5], m6 = csr[e + 6], m7 = csr[e + 7];
        EDGE_BODY(m0, a0, b0); EDGE_BODY(m1, a1, b1);
        EDGE_BODY(m2, a2, b2); EDGE_BODY(m3, a3, b3);
        EDGE_BODY(m4, a0, b0); EDGE_BODY(m5, a1, b1);
        EDGE_BODY(m6, a2, b2); EDGE_BODY(m7, a3, b3);
    }
    for (; e + 2 <= end; e += 2) {
        uint_t m0 = csr[e + 0], m1 = csr[e + 1];
        EDGE_BODY(m0, a0, b0); EDGE_BODY(m1, a1, b1);
    }
    if (e < end) {
        uint_t m0 = csr[e];
        EDGE_BODY(m0, a2, b2);
    }
    float valA = coef * ((a0 + a1) + (a2 + a3));
    float valB = coef * ((b0 + b1) + (b2 + b3));
    size_t idx = (size_t)row * 32 + lane;
    term_out[idx] = (uint_t)f2bf(valA) | ((uint_t)f2bf(valB) << 16);
    if (first) {
        float2 xv = x[idx];
        acc[idx] = make_float2(xv.x + valA, xv.y + valB);
    } else {
        float2 av = acc[idx];
        acc[idx] = make_float2(av.x + valA, av.y + valB);
    }
}

extern "C" void kernel_launch(void* const* d_in, const int* in_sizes, int n_in,
                              void* d_out, int out_size, void* d_ws, size_t ws_size,
                              hipStream_t stream) {
    const float* x    = (const float*)d_in[0];
    const int*   esrc = (const int*)d_in[1];
    const int*   edst = (const int*)d_in[2];
    const float* ew   = (const float*)d_in[3];
    const float* tp   = (const float*)d_in[4];
    float* out = (float*)d_out;

    const int E = in_sizes[1];
    const int N = N_NODES;
    const int NC = N * C_CH;

    int* ws = (int*)d_ws;
    int* row_ptr = ws;                          // N+1, pad to 50008
    int* cnt     = ws + 50008;                  // N
    int* pos     = ws + 100008;                 // N
    int* blk_sum = ws + 150008;                 // 64, pad to 150080
    uint_t* csr  = (uint_t*)(ws + 150080);      // E packed entries
    uint_t* xb     = (uint_t*)(ws + 150080 + E);     // NC/2 bf16x2
    uint_t* term_a = xb + (size_t)NC / 2;            // NC/2
    uint_t* term_b = term_a + (size_t)NC / 2;        // NC/2

    // CSR build
    hipMemsetAsync(cnt, 0, (size_t)N * sizeof(int), stream);
    hist_kernel<<<(E + 255) / 256, 256, 0, stream>>>(esrc, cnt, E);
    const int nb = (N + 1023) / 1024;  // 49
    scan1_kernel<<<nb, 1024, 0, stream>>>(cnt, row_ptr, blk_sum, N);
    scan2_kernel<<<1, 64, 0, stream>>>(blk_sum, nb);
    scan3_kernel<<<(N + 255) / 256, 256, 0, stream>>>(row_ptr, pos, blk_sum, cnt, N);
    scatter_kernel<<<(E + 255) / 256, 256, 0, stream>>>(esrc, edst, ew, pos, csr, E);

    // x -> bf16x2
    cvt_kernel<<<(NC / 2 + 255) / 256, 256, 0, stream>>>((const float2*)x,
                                                         xb, NC / 2);

    const int rows_per_block = 256 / 32;  // 8 rows per block (half-wave per row)
    const int tgrid = (N + rows_per_block - 1) / rows_per_block;

    // k=1 gathers xb, seeds acc = x + term1
    taylor_kernel<<<tgrid, 256, 0, stream>>>(row_ptr, csr, xb, term_b,
                                             (float2*)out, (const float2*)x, tp,
                                             1.0f, N, 1);
    const uint_t* tin = term_b;
    uint_t* tout = term_a;
    for (int k = 2; k <= M_TERMS; ++k) {
        taylor_kernel<<<tgrid, 256, 0, stream>>>(row_ptr, csr, tin, tout,
                                                 (float2*)out, (const float2*)x, tp,
                                                 1.0f / (float)k, N, 0);
        const uint_t* tmp = tin;
        tin = tout;
        tout = (uint_t*)tmp;
    }
}

// Round 6
// 295.138 us; speedup vs baseline: 23.2682x; 1.0531x over previous
//
#include <hip/hip_runtime.h>

#define N_NODES 50000
#define C_CH 64
#define M_TERMS 8   // ||-t*L||inf <= ~1.0 worst case; tail after 8 terms < 3e-6

typedef unsigned short ushort_t;
typedef unsigned int uint_t;

__device__ __forceinline__ float bf2f(uint_t h16) {  // low 16 bits = bf16
    return __uint_as_float(h16 << 16);
}
__device__ __forceinline__ ushort_t f2bf(float f) {  // round-to-nearest-even
    uint_t u = __float_as_uint(f);
    u += 0x7FFFu + ((u >> 16) & 1u);
    return (ushort_t)(u >> 16);
}

// ---------------- CSR build ----------------

__global__ void hist_kernel(const int* __restrict__ src, int* __restrict__ cnt, int E) {
    int e = blockIdx.x * blockDim.x + threadIdx.x;
    if (e < E) atomicAdd(&cnt[src[e]], 1);
}

// pass 1: per-block (1024) inclusive scan -> row_ptr[i+1]; block totals -> blk_sum
__global__ void scan1_kernel(const int* __restrict__ cnt, int* __restrict__ row_ptr,
                             int* __restrict__ blk_sum, int n) {
    __shared__ int wsum[16];
    const int tid = threadIdx.x;
    const int lane = tid & 63;
    const int wv = tid >> 6;
    int i = blockIdx.x * 1024 + tid;
    int v = (i < n) ? cnt[i] : 0;
    int s = v;
    #pragma unroll
    for (int off = 1; off < 64; off <<= 1) {
        int u = __shfl_up(s, off, 64);
        if (lane >= off) s += u;
    }
    if (lane == 63) wsum[wv] = s;
    __syncthreads();
    if (wv == 0) {
        int ws = (lane < 16) ? wsum[lane] : 0;
        #pragma unroll
        for (int off = 1; off < 16; off <<= 1) {
            int u = __shfl_up(ws, off, 64);
            if (lane >= off) ws += u;
        }
        if (lane < 16) wsum[lane] = ws;
    }
    __syncthreads();
    int incl = s + ((wv == 0) ? 0 : wsum[wv - 1]);
    if (i < n) row_ptr[i + 1] = incl;
    if (tid == 1023) blk_sum[blockIdx.x] = incl;
}

// pass 2+3 fused: every block redundantly wave-scans the <=64 block sums,
// then adds offsets and emits scatter cursors pos[i].
__global__ void scan3_kernel(int* __restrict__ row_ptr, int* __restrict__ pos,
                             const int* __restrict__ blk_sum, const int* __restrict__ cnt,
                             int n, int nb) {
    __shared__ int soff[64];
    const int tid = threadIdx.x;
    if (tid < 64) {
        int v = (tid < nb) ? blk_sum[tid] : 0;
        int s = v;
        #pragma unroll
        for (int off = 1; off < 64; off <<= 1) {
            int u = __shfl_up(s, off, 64);
            if (tid >= off) s += u;
        }
        soff[tid] = s - v;  // exclusive prefix of block sums
    }
    __syncthreads();
    int i = blockIdx.x * blockDim.x + tid;
    if (i < n) {
        int incl = row_ptr[i + 1] + soff[i >> 10];
        row_ptr[i + 1] = incl;
        pos[i] = incl - cnt[i];
    }
    if (i == 0) row_ptr[0] = 0;
}

// packed CSR entry: low16 = dst (N<65536), high16 = bf16(w)
__global__ void scatter_kernel(const int* __restrict__ src, const int* __restrict__ dst,
                               const float* __restrict__ w, int* __restrict__ pos,
                               uint_t* __restrict__ csr, int E) {
    int e = blockIdx.x * blockDim.x + threadIdx.x;
    if (e < E) {
        int r = src[e];
        int p = atomicAdd(&pos[r], 1);
        csr[p] = (uint_t)dst[e] | ((uint_t)f2bf(w[e]) << 16);
    }
}

// x (fp32) -> xb (bf16x2 packed); 2 elems/thread
__global__ void cvt_kernel(const float2* __restrict__ x, uint_t* __restrict__ xb, int n2) {
    int i = blockIdx.x * blockDim.x + threadIdx.x;
    if (i < n2) {
        float2 v = x[i];
        xb[i] = (uint_t)f2bf(v.x) | ((uint_t)f2bf(v.y) << 16);
    }
}

// ---------------- diffusion ----------------
// HALF-wave per row: 32 lanes x (bf16x2) = 128B row; 2 rows/wave, 8-deep unroll.
// Writes only its bf16 term buffer (acc handled separately).

#define EDGE_BODY(M, SA, SB)                                     \
    {                                                            \
        uint_t _m = (M);                                         \
        float _w = bf2f(_m >> 16);                               \
        uint_t _v = term_in[(size_t)(_m & 0xFFFFu) * 32 + lane]; \
        SA = fmaf(_w, bf2f(_v & 0xFFFFu), SA);                   \
        SB = fmaf(_w, bf2f(_v >> 16), SB);                       \
    }

__global__ __launch_bounds__(256) void
taylor_kernel(const int* __restrict__ row_ptr, const uint_t* __restrict__ csr,
              const uint_t* __restrict__ term_in, uint_t* __restrict__ term_out,
              float2* __restrict__ acc, const float2* __restrict__ x,
              const float* __restrict__ t_ptr,
              float inv_k, int n, int mode) {  // mode: 0=term only, 1=first+acc, 2=acc RMW
    int row = (blockIdx.x * blockDim.x + threadIdx.x) >> 5;
    int lane = threadIdx.x & 31;
    if (row >= n) return;
    float t = fmaxf(t_ptr[0], 1e-8f);
    float coef = -t * inv_k;
    int beg = row_ptr[row];
    int end = row_ptr[row + 1];

    float a0 = 0.f, a1 = 0.f, a2 = 0.f, a3 = 0.f;
    float b0 = 0.f, b1 = 0.f, b2 = 0.f, b3 = 0.f;
    int e = beg;
    for (; e + 8 <= end; e += 8) {
        uint_t m0 = csr[e + 0], m1 = csr[e + 1], m2 = csr[e + 2], m3 = csr[e + 3];
        uint_t m4 = csr[e + 4], m5 = csr[e + 5], m6 = csr[e + 6], m7 = csr[e + 7];
        EDGE_BODY(m0, a0, b0); EDGE_BODY(m1, a1, b1);
        EDGE_BODY(m2, a2, b2); EDGE_BODY(m3, a3, b3);
        EDGE_BODY(m4, a0, b0); EDGE_BODY(m5, a1, b1);
        EDGE_BODY(m6, a2, b2); EDGE_BODY(m7, a3, b3);
    }
    for (; e + 2 <= end; e += 2) {
        uint_t m0 = csr[e + 0], m1 = csr[e + 1];
        EDGE_BODY(m0, a0, b0); EDGE_BODY(m1, a1, b1);
    }
    if (e < end) {
        uint_t m0 = csr[e];
        EDGE_BODY(m0, a2, b2);
    }
    float valA = coef * ((a0 + a1) + (a2 + a3));
    float valB = coef * ((b0 + b1) + (b2 + b3));
    size_t idx = (size_t)row * 32 + lane;
    term_out[idx] = (uint_t)f2bf(valA) | ((uint_t)f2bf(valB) << 16);
    if (mode == 1) {
        float2 xv = x[idx];
        acc[idx] = make_float2(xv.x + valA, xv.y + valB);
    } else if (mode == 2) {
        float2 av = acc[idx];
        acc[idx] = make_float2(av.x + valA, av.y + valB);
    }
}

// out = x + sum_k term_k  (terms contiguous, stride elements apart)
__global__ __launch_bounds__(256) void
final_kernel(const float2* __restrict__ x, const uint_t* __restrict__ terms,
             size_t stride, float2* __restrict__ out, int n2) {
    int i = blockIdx.x * blockDim.x + threadIdx.x;
    if (i >= n2) return;
    float sa = 0.f, sb = 0.f;
    #pragma unroll
    for (int k = 0; k < M_TERMS; ++k) {
        uint_t v = terms[(size_t)k * stride + i];
        sa += bf2f(v & 0xFFFFu);
        sb += bf2f(v >> 16);
    }
    float2 xv = x[i];
    out[i] = make_float2(xv.x + sa, xv.y + sb);
}

extern "C" void kernel_launch(void* const* d_in, const int* in_sizes, int n_in,
                              void* d_out, int out_size, void* d_ws, size_t ws_size,
                              hipStream_t stream) {
    const float* x    = (const float*)d_in[0];
    const int*   esrc = (const int*)d_in[1];
    const int*   edst = (const int*)d_in[2];
    const float* ew   = (const float*)d_in[3];
    const float* tp   = (const float*)d_in[4];
    float* out = (float*)d_out;

    const int E = in_sizes[1];
    const int N = N_NODES;
    const int NC = N * C_CH;
    const size_t TERM = (size_t)NC / 2;  // uints per bf16x2 buffer

    int* ws = (int*)d_ws;
    int* row_ptr = ws;                          // N+1, pad to 50008
    int* cnt     = ws + 50008;                  // N
    int* pos     = ws + 100008;                 // N
    int* blk_sum = ws + 150008;                 // 64, pad to 150080
    uint_t* csr  = (uint_t*)(ws + 150080);      // E packed entries
    uint_t* xb   = (uint_t*)(ws + 150080 + E);  // TERM

    // path A (term-buffer accumulation) needs xb + 8 term buffers
    const size_t needA = ((size_t)150080 + E) * 4 + (1 + M_TERMS) * TERM * 4;
    const int pathA = (ws_size >= needA);

    // CSR build
    hipMemsetAsync(cnt, 0, (size_t)N * sizeof(int), stream);
    hist_kernel<<<(E + 255) / 256, 256, 0, stream>>>(esrc, cnt, E);
    const int nb = (N + 1023) / 1024;  // 49
    scan1_kernel<<<nb, 1024, 0, stream>>>(cnt, row_ptr, blk_sum, N);
    scan3_kernel<<<(N + 255) / 256, 256, 0, stream>>>(row_ptr, pos, blk_sum, cnt, N, nb);
    scatter_kernel<<<(E + 255) / 256, 256, 0, stream>>>(esrc, edst, ew, pos, csr, E);

    // x -> bf16x2
    cvt_kernel<<<(NC / 2 + 255) / 256, 256, 0, stream>>>((const float2*)x, xb, NC / 2);

    const int rows_per_block = 256 / 32;  // 8 rows per block (half-wave per row)
    const int tgrid = (N + rows_per_block - 1) / rows_per_block;
    const int fgrid = (NC / 2 + 255) / 256;

    if (pathA) {
        uint_t* terms = xb + TERM;  // 8 consecutive buffers
        // k=1 gathers xb -> terms[0]
        taylor_kernel<<<tgrid, 256, 0, stream>>>(row_ptr, csr, xb, terms, nullptr,
                                                 nullptr, tp, 1.0f, N, 0);
        for (int k = 2; k <= M_TERMS; ++k) {
            taylor_kernel<<<tgrid, 256, 0, stream>>>(row_ptr, csr,
                                                     terms + (size_t)(k - 2) * TERM,
                                                     terms + (size_t)(k - 1) * TERM,
                                                     nullptr, nullptr, tp,
                                                     1.0f / (float)k, N, 0);
        }
        final_kernel<<<fgrid, 256, 0, stream>>>((const float2*)x, terms, TERM,
                                                (float2*)out, NC / 2);
    } else {
        // fallback: acc RMW in d_out (round-5 scheme)
        uint_t* term_a = xb + TERM;
        uint_t* term_b = term_a + TERM;
        taylor_kernel<<<tgrid, 256, 0, stream>>>(row_ptr, csr, xb, term_b,
                                                 (float2*)out, (const float2*)x, tp,
                                                 1.0f, N, 1);
        const uint_t* tin = term_b;
        uint_t* tout = term_a;
        for (int k = 2; k <= M_TERMS; ++k) {
            taylor_kernel<<<tgrid, 256, 0, stream>>>(row_ptr, csr, tin, tout,
                                                     (float2*)out, (const float2*)x, tp,
                                                     1.0f / (float)k, N, 2);
            const uint_t* tmp = tin;
            tin = tout;
            tout = (uint_t*)tmp;
        }
    }
}

// Round 7
// 276.246 us; speedup vs baseline: 24.8594x; 1.0684x over previous
//
#include <hip/hip_runtime.h>

#define N_NODES 50000
#define C_CH 64
#define M_TERMS 8   // ||-t*L||inf <= ~1.0 worst case; tail after 8 terms < 3e-6

typedef unsigned short ushort_t;
typedef unsigned int uint_t;

__device__ __forceinline__ float bf2f(uint_t h16) {  // low 16 bits = bf16
    return __uint_as_float(h16 << 16);
}
__device__ __forceinline__ ushort_t f2bf(float f) {  // round-to-nearest-even
    uint_t u = __float_as_uint(f);
    u += 0x7FFFu + ((u >> 16) & 1u);
    return (ushort_t)(u >> 16);
}

// ---------------- CSR build ----------------

__global__ void hist_kernel(const int* __restrict__ src, int* __restrict__ cnt, int E) {
    int e = blockIdx.x * blockDim.x + threadIdx.x;
    if (e < E) atomicAdd(&cnt[src[e]], 1);
}

// pass 1: per-block (1024) inclusive scan -> row_ptr[i+1]; block totals -> blk_sum
__global__ void scan1_kernel(const int* __restrict__ cnt, int* __restrict__ row_ptr,
                             int* __restrict__ blk_sum, int n) {
    __shared__ int wsum[16];
    const int tid = threadIdx.x;
    const int lane = tid & 63;
    const int wv = tid >> 6;
    int i = blockIdx.x * 1024 + tid;
    int v = (i < n) ? cnt[i] : 0;
    int s = v;
    #pragma unroll
    for (int off = 1; off < 64; off <<= 1) {
        int u = __shfl_up(s, off, 64);
        if (lane >= off) s += u;
    }
    if (lane == 63) wsum[wv] = s;
    __syncthreads();
    if (wv == 0) {
        int ws = (lane < 16) ? wsum[lane] : 0;
        #pragma unroll
        for (int off = 1; off < 16; off <<= 1) {
            int u = __shfl_up(ws, off, 64);
            if (lane >= off) ws += u;
        }
        if (lane < 16) wsum[lane] = ws;
    }
    __syncthreads();
    int incl = s + ((wv == 0) ? 0 : wsum[wv - 1]);
    if (i < n) row_ptr[i + 1] = incl;
    if (tid == 1023) blk_sum[blockIdx.x] = incl;
}

// pass 2+3 fused: every block redundantly wave-scans the <=64 block sums,
// then adds offsets and emits scatter cursors pos[i].
__global__ void scan3_kernel(int* __restrict__ row_ptr, int* __restrict__ pos,
                             const int* __restrict__ blk_sum, const int* __restrict__ cnt,
                             int n, int nb) {
    __shared__ int soff[64];
    const int tid = threadIdx.x;
    if (tid < 64) {
        int v = (tid < nb) ? blk_sum[tid] : 0;
        int s = v;
        #pragma unroll
        for (int off = 1; off < 64; off <<= 1) {
            int u = __shfl_up(s, off, 64);
            if (tid >= off) s += u;
        }
        soff[tid] = s - v;  // exclusive prefix of block sums
    }
    __syncthreads();
    int i = blockIdx.x * blockDim.x + tid;
    if (i < n) {
        int incl = row_ptr[i + 1] + soff[i >> 10];
        row_ptr[i + 1] = incl;
        pos[i] = incl - cnt[i];
    }
    if (i == 0) row_ptr[0] = 0;
}

// fused: scatter packed CSR entries + convert x -> bf16x4 (independent phases)
__global__ void scatter_cvt_kernel(const int* __restrict__ src, const int* __restrict__ dst,
                                   const float* __restrict__ w, int* __restrict__ pos,
                                   uint_t* __restrict__ csr, int E,
                                   const float4* __restrict__ x, uint2* __restrict__ xb,
                                   int n4) {
    int i0 = blockIdx.x * blockDim.x + threadIdx.x;
    int stride = gridDim.x * blockDim.x;
    for (int e = i0; e < E; e += stride) {
        int r = src[e];
        int p = atomicAdd(&pos[r], 1);
        csr[p] = (uint_t)dst[e] | ((uint_t)f2bf(w[e]) << 16);
    }
    for (int i = i0; i < n4; i += stride) {
        float4 v = x[i];
        xb[i] = make_uint2((uint_t)f2bf(v.x) | ((uint_t)f2bf(v.y) << 16),
                           (uint_t)f2bf(v.z) | ((uint_t)f2bf(v.w) << 16));
    }
}

// ---------------- diffusion ----------------
// QUARTER-wave per row: 16 lanes x uint2 (4 bf16 ch) = 128B row; 4 rows/wave.
// Uniform clamped 8-deep loop -> 32 outstanding gathers per wave, no remainder.

__global__ __launch_bounds__(256) void
taylor_kernel(const int* __restrict__ row_ptr, const uint_t* __restrict__ csr,
              const uint2* __restrict__ term_in, uint2* __restrict__ term_out,
              float4* __restrict__ acc, const float4* __restrict__ x,
              const float* __restrict__ t_ptr,
              float inv_k, int n, int mode) {  // mode: 0=term only, 1=first+acc, 2=acc RMW
    int gid = blockIdx.x * blockDim.x + threadIdx.x;
    int row = gid >> 4;
    if (row >= n) return;
    int lane = gid & 15;
    float t = fmaxf(t_ptr[0], 1e-8f);
    float coef = -t * inv_k;
    int beg = row_ptr[row];
    int end = row_ptr[row + 1];

    float s0 = 0.f, s1 = 0.f, s2 = 0.f, s3 = 0.f;
    float r0 = 0.f, r1 = 0.f, r2 = 0.f, r3 = 0.f;
    for (int e = beg; e < end; e += 8) {
        float ww[8];
        uint2 vv[8];
        #pragma unroll
        for (int j = 0; j < 8; ++j) {
            int ee = e + j;
            int ec = (ee < end) ? ee : (end - 1);  // clamp: repeat last edge
            uint_t m = csr[ec];
            ww[j] = (ee < end) ? bf2f(m >> 16) : 0.f;  // zero weight for clamped
            vv[j] = term_in[(size_t)(m & 0xFFFFu) * 16 + lane];
        }
        #pragma unroll
        for (int j = 0; j < 8; j += 2) {
            float wA = ww[j];     uint2 vA = vv[j];
            float wB = ww[j + 1]; uint2 vB = vv[j + 1];
            s0 = fmaf(wA, bf2f(vA.x & 0xFFFFu), s0);
            s1 = fmaf(wA, bf2f(vA.x >> 16),     s1);
            s2 = fmaf(wA, bf2f(vA.y & 0xFFFFu), s2);
            s3 = fmaf(wA, bf2f(vA.y >> 16),     s3);
            r0 = fmaf(wB, bf2f(vB.x & 0xFFFFu), r0);
            r1 = fmaf(wB, bf2f(vB.x >> 16),     r1);
            r2 = fmaf(wB, bf2f(vB.y & 0xFFFFu), r2);
            r3 = fmaf(wB, bf2f(vB.y >> 16),     r3);
        }
    }
    float v0 = coef * (s0 + r0);
    float v1 = coef * (s1 + r1);
    float v2 = coef * (s2 + r2);
    float v3 = coef * (s3 + r3);
    size_t idx = (size_t)row * 16 + lane;
    term_out[idx] = make_uint2((uint_t)f2bf(v0) | ((uint_t)f2bf(v1) << 16),
                               (uint_t)f2bf(v2) | ((uint_t)f2bf(v3) << 16));
    if (mode == 1) {
        float4 xv = x[idx];
        acc[idx] = make_float4(xv.x + v0, xv.y + v1, xv.z + v2, xv.w + v3);
    } else if (mode == 2) {
        float4 av = acc[idx];
        acc[idx] = make_float4(av.x + v0, av.y + v1, av.z + v2, av.w + v3);
    }
}

// out = x + sum_k term_k  (terms contiguous, stride uint2-elements apart)
__global__ __launch_bounds__(256) void
final_kernel(const float4* __restrict__ x, const uint2* __restrict__ terms,
             size_t stride, float4* __restrict__ out, int n4) {
    int i = blockIdx.x * blockDim.x + threadIdx.x;
    if (i >= n4) return;
    float a = 0.f, b = 0.f, c = 0.f, d = 0.f;
    #pragma unroll
    for (int k = 0; k < M_TERMS; ++k) {
        uint2 v = terms[(size_t)k * stride + i];
        a += bf2f(v.x & 0xFFFFu);
        b += bf2f(v.x >> 16);
        c += bf2f(v.y & 0xFFFFu);
        d += bf2f(v.y >> 16);
    }
    float4 xv = x[i];
    out[i] = make_float4(xv.x + a, xv.y + b, xv.z + c, xv.w + d);
}

extern "C" void kernel_launch(void* const* d_in, const int* in_sizes, int n_in,
                              void* d_out, int out_size, void* d_ws, size_t ws_size,
                              hipStream_t stream) {
    const float* x    = (const float*)d_in[0];
    const int*   esrc = (const int*)d_in[1];
    const int*   edst = (const int*)d_in[2];
    const float* ew   = (const float*)d_in[3];
    const float* tp   = (const float*)d_in[4];
    float* out = (float*)d_out;

    const int E = in_sizes[1];
    const int N = N_NODES;
    const int NC = N * C_CH;
    const size_t TERM2 = (size_t)NC / 4;  // uint2 elements per bf16 buffer

    int* ws = (int*)d_ws;
    int* row_ptr = ws;                          // N+1, pad to 50008
    int* cnt     = ws + 50008;                  // N
    int* pos     = ws + 100008;                 // N
    int* blk_sum = ws + 150008;                 // 64, pad to 150080
    uint_t* csr  = (uint_t*)(ws + 150080);      // E packed entries
    uint2* xb    = (uint2*)(ws + 150080 + E + (E & 1));  // TERM2, 8B aligned
    // path A (term-buffer accumulation) needs xb + 8 term buffers
    const size_t needA = ((size_t)150080 + E + 1) * 4 + (1 + M_TERMS) * TERM2 * 8;
    const int pathA = (ws_size >= needA);

    // CSR build
    hipMemsetAsync(cnt, 0, (size_t)N * sizeof(int), stream);
    hist_kernel<<<(E + 255) / 256, 256, 0, stream>>>(esrc, cnt, E);
    const int nb = (N + 1023) / 1024;  // 49
    scan1_kernel<<<nb, 1024, 0, stream>>>(cnt, row_ptr, blk_sum, N);
    scan3_kernel<<<(N + 255) / 256, 256, 0, stream>>>(row_ptr, pos, blk_sum, cnt, N, nb);
    scatter_cvt_kernel<<<2048, 256, 0, stream>>>(esrc, edst, ew, pos, csr, E,
                                                 (const float4*)x, xb, NC / 4);

    const int tgrid = (N * 16 + 255) / 256;   // quarter-wave per row
    const int fgrid = (NC / 4 + 255) / 256;

    if (pathA) {
        uint2* terms = xb + TERM2;  // 8 consecutive buffers
        // k=1 gathers xb -> terms[0]
        taylor_kernel<<<tgrid, 256, 0, stream>>>(row_ptr, csr, xb, terms, nullptr,
                                                 nullptr, tp, 1.0f, N, 0);
        for (int k = 2; k <= M_TERMS; ++k) {
            taylor_kernel<<<tgrid, 256, 0, stream>>>(row_ptr, csr,
                                                     terms + (size_t)(k - 2) * TERM2,
                                                     terms + (size_t)(k - 1) * TERM2,
                                                     nullptr, nullptr, tp,
                                                     1.0f / (float)k, N, 0);
        }
        final_kernel<<<fgrid, 256, 0, stream>>>((const float4*)x, terms, TERM2,
                                                (float4*)out, NC / 4);
    } else {
        // fallback: acc RMW in d_out
        uint2* term_a = xb + TERM2;
        uint2* term_b = term_a + TERM2;
        taylor_kernel<<<tgrid, 256, 0, stream>>>(row_ptr, csr, xb, term_b,
                                                 (float4*)out, (const float4*)x, tp,
                                                 1.0f, N, 1);
        const uint2* tin = term_b;
        uint2* tout = term_a;
        for (int k = 2; k <= M_TERMS; ++k) {
            taylor_kernel<<<tgrid, 256, 0, stream>>>(row_ptr, csr, tin, tout,
                                                     (float4*)out, (const float4*)x, tp,
                                                     1.0f / (float)k, N, 2);
            const uint2* tmp = tin;
            tin = tout;
            tout = (uint2*)tmp;
        }
    }
}